// Round 17
// baseline (150.203 us; speedup 1.0000x reference)
//
#include <hip/hip_runtime.h>
#include <hip/hip_bf16.h>

// B=2, T=2048, C=1024, H=16, D=64, M=B*T=4096
// GEMMs: exact integer math via i8 MFMA (i32 accum, |dot| <= 130K exact).

typedef __attribute__((ext_vector_type(8))) short bf16x8;
typedef __attribute__((ext_vector_type(4))) float f32x4;
typedef __attribute__((ext_vector_type(4))) int i32x4;

__device__ __forceinline__ f32x4 mfma16(bf16x8 a, bf16x8 b, f32x4 c) {
    return __builtin_amdgcn_mfma_f32_16x16x32_bf16(a, b, c, 0, 0, 0);
}

__device__ __forceinline__ i32x4 mfma_i8(i32x4 a, i32x4 b, i32x4 c) {
    return __builtin_amdgcn_mfma_i32_16x16x64_i8(a, b, c, 0, 0, 0);
}

__device__ __forceinline__ unsigned short f2bf(float f) {
    unsigned int u = __float_as_uint(f);
    unsigned int r = (u + 0x7fffu + ((u >> 16) & 1u)) >> 16;
    return (unsigned short)r;
}

__device__ __forceinline__ float bf2f(unsigned short u) {
    return __uint_as_float(((unsigned int)u) << 16);
}

__device__ __forceinline__ unsigned int cvtpk_bf16(float lo, float hi) {
    unsigned int r;
    asm("v_cvt_pk_bf16_f32 %0, %1, %2" : "=v"(r) : "v"(lo), "v"(hi));
    return r;
}

__device__ __forceinline__ float exp2_fast(float x) {
    float r;
    asm("v_exp_f32 %0, %1" : "=v"(r) : "v"(x));
    return r;
}

__device__ __forceinline__ void gload_lds16(const void* g, void* l) {
    __builtin_amdgcn_global_load_lds((const __attribute__((address_space(1))) unsigned int*)g,
                                     (__attribute__((address_space(3))) unsigned int*)l, 16, 0, 0);
}

__device__ __forceinline__ int pack4i8(float a, float b, float c, float d) {
    unsigned int u = ((unsigned int)((int)a & 255)) | (((unsigned int)((int)b & 255)) << 8) |
                     (((unsigned int)((int)c & 255)) << 16) | (((unsigned int)((int)d & 255)) << 24);
    return (int)u;
}

__device__ __forceinline__ float wredsum(float v) {
#pragma unroll
    for (int o = 32; o > 0; o >>= 1) v += __shfl_xor(v, o);
    return v;
}
__device__ __forceinline__ float wredmax(float v) {
#pragma unroll
    for (int o = 32; o > 0; o >>= 1) v = fmaxf(v, __shfl_xor(v, o));
    return v;
}

// ------- fused: rmsnorm+absmax-quant of x (3 planes) AND weight |w| partials -
// blocks 0..4095: actquant on x row m; blocks 4096..4223: wabssum partials.
__global__ __launch_bounds__(256) void prep(const float* __restrict__ x, const float* __restrict__ g0,
                                            const float* __restrict__ g1, const float* __restrict__ g2,
                                            signed char* __restrict__ aq, float* __restrict__ ascale,
                                            const float* __restrict__ w0, const float* __restrict__ w1,
                                            const float* __restrict__ w2, const float* __restrict__ w3,
                                            float* __restrict__ part) {
    int tid = threadIdx.x;
    int wid = tid >> 6, lid = tid & 63;
    __shared__ float red[4];
    if (blockIdx.x >= 4096) {
        int bb = blockIdx.x - 4096;
        int widx = bb >> 5, b = bb & 31;
        const float* w = (widx == 0) ? w0 : (widx == 1) ? w1 : (widx == 2) ? w2 : w3;
        const float4* w4 = (const float4*)w;
        float s = 0.f;
        int base = b * 8192 + tid;
#pragma unroll
        for (int i = 0; i < 32; ++i) {
            float4 v = w4[base + i * 256];
            s += fabsf(v.x) + fabsf(v.y) + fabsf(v.z) + fabsf(v.w);
        }
        s = wredsum(s);
        if (lid == 0) red[wid] = s;
        __syncthreads();
        if (tid == 0) part[bb] = red[0] + red[1] + red[2] + red[3];
        return;
    }
    int m = blockIdx.x;
    float4 xv = ((const float4*)(x + (size_t)m * 1024))[tid];
    float ss = xv.x * xv.x + xv.y * xv.y + xv.z * xv.z + xv.w * xv.w;
    ss = wredsum(ss);
    if (lid == 0) red[wid] = ss;
    __syncthreads();
    float rstd = rsqrtf((red[0] + red[1] + red[2] + red[3]) * (1.f / 1024.f) + 1e-6f);
    const float* gs[3] = {g0, g1, g2};
#pragma unroll
    for (int p = 0; p < 3; ++p) {
        float4 gv = ((const float4*)gs[p])[tid];
        float a0 = xv.x * gv.x * rstd, a1 = xv.y * gv.y * rstd;
        float a2 = xv.z * gv.z * rstd, a3 = xv.w * gv.w * rstd;
        float am = fmaxf(fmaxf(fabsf(a0), fabsf(a1)), fmaxf(fabsf(a2), fabsf(a3)));
        am = wredmax(am);
        __syncthreads();
        if (lid == 0) red[wid] = am;
        __syncthreads();
        float rm = fmaxf(fmaxf(red[0], red[1]), fmaxf(red[2], red[3]));
        float scale = 127.f / fmaxf(rm, 1e-5f);
        float q0 = fminf(fmaxf(rintf(a0 * scale), -128.f), 127.f);
        float q1 = fminf(fmaxf(rintf(a1 * scale), -128.f), 127.f);
        float q2 = fminf(fmaxf(rintf(a2 * scale), -128.f), 127.f);
        float q3 = fminf(fmaxf(rintf(a3 * scale), -128.f), 127.f);
        ((int*)(aq + (size_t)p * 4194304 + (size_t)m * 1024))[tid] = pack4i8(q0, q1, q2, q3);
        if (tid == 0) ascale[p * 4096 + m] = scale;
    }
}

// ---------------- ternary weight quant -> i8 {-1,0,1} -----------------------
__global__ __launch_bounds__(256) void wquant(const float* __restrict__ w0, const float* __restrict__ w1,
                                              const float* __restrict__ w2, const float* __restrict__ w3,
                                              const float* __restrict__ part, signed char* __restrict__ wq8) {
    int widx = blockIdx.x >> 6, b = blockIdx.x & 63;
    const float* w = (widx == 0) ? w0 : (widx == 1) ? w1 : (widx == 2) ? w2 : w3;
    float s = 0.f;
#pragma unroll
    for (int i = 0; i < 32; ++i) s += part[widx * 32 + i];
    s = fmaxf(s * (1.f / 1048576.f), 1e-5f);
    float inv = 1.f / s;
    const float4* w4 = (const float4*)w;
    int* dst = (int*)(wq8 + (size_t)widx * 1048576);
    int tid = threadIdx.x;
#pragma unroll
    for (int it = 0; it < 16; ++it) {
        int i4 = b * 4096 + it * 256 + tid;
        float4 v = w4[i4];
        float q0 = fminf(fmaxf(rintf(v.x * inv), -1.f), 1.f);
        float q1 = fminf(fmaxf(rintf(v.y * inv), -1.f), 1.f);
        float q2 = fminf(fmaxf(rintf(v.z * inv), -1.f), 1.f);
        float q3 = fminf(fmaxf(rintf(v.w * inv), -1.f), 1.f);
        dst[i4] = pack4i8(q0, q1, q2, q3);
    }
}

// ------- rmsnorm+absmax-quant of y (bf16 input, 1 plane) --------------------
__global__ __launch_bounds__(256) void actquant_y(const unsigned short* __restrict__ y,
                                                  const float* __restrict__ g,
                                                  signed char* __restrict__ aq, float* __restrict__ ascale) {
    int m = blockIdx.x, tid = threadIdx.x;
    int wid = tid >> 6, lid = tid & 63;
    __shared__ float red[4];
    ushort4 uv = ((const ushort4*)(y + (size_t)m * 1024))[tid];
    float4 xv;
    xv.x = bf2f(uv.x);
    xv.y = bf2f(uv.y);
    xv.z = bf2f(uv.z);
    xv.w = bf2f(uv.w);
    float ss = xv.x * xv.x + xv.y * xv.y + xv.z * xv.z + xv.w * xv.w;
    ss = wredsum(ss);
    if (lid == 0) red[wid] = ss;
    __syncthreads();
    float rstd = rsqrtf((red[0] + red[1] + red[2] + red[3]) * (1.f / 1024.f) + 1e-6f);
    float4 gv = ((const float4*)g)[tid];
    float a0 = xv.x * gv.x * rstd, a1 = xv.y * gv.y * rstd;
    float a2 = xv.z * gv.z * rstd, a3 = xv.w * gv.w * rstd;
    float am = fmaxf(fmaxf(fabsf(a0), fabsf(a1)), fmaxf(fabsf(a2), fabsf(a3)));
    am = wredmax(am);
    __syncthreads();
    if (lid == 0) red[wid] = am;
    __syncthreads();
    float rm = fmaxf(fmaxf(red[0], red[1]), fmaxf(red[2], red[3]));
    float scale = 127.f / fmaxf(rm, 1e-5f);
    float q0 = fminf(fmaxf(rintf(a0 * scale), -128.f), 127.f);
    float q1 = fminf(fmaxf(rintf(a1 * scale), -128.f), 127.f);
    float q2 = fminf(fmaxf(rintf(a2 * scale), -128.f), 127.f);
    float q3 = fminf(fmaxf(rintf(a3 * scale), -128.f), 127.f);
    ((int*)(aq + (size_t)m * 1024))[tid] = pack4i8(q0, q1, q2, q3);
    if (tid == 0) ascale[m] = scale;
}

// ------------- 128x128-tile i8 GEMM core (dbuf + XOR-swizzled LDS) ----------
template <int MODE>
__device__ __forceinline__ void gemm_core(const signed char* __restrict__ A,
                                          const float* __restrict__ asc,
                                          const signed char* __restrict__ W, float s_w,
                                          void* __restrict__ outp, int bm, int bn,
                                          char* As, char* Bs) {
    int tid = threadIdx.x;
    int w = tid >> 6, l = tid & 63;
    int wr = w >> 1, wc = w & 1;
    int lr = l & 15, lh = l >> 4;
    i32x4 acc[4][4] = {};
    int srow = l >> 3;
    int scolb = (((l & 7) ^ srow)) * 16;
    int key16 = (lr & 7) * 16;
    const signed char* Ab = A + (size_t)(bm * 128) * 1024;
    const signed char* Wb = W + (size_t)(bn * 128) * 1024;

    auto STAGE = [&](int kt, int buf) {
        int k0 = kt * 128;
        char* Ad = As + buf * 16384;
        char* Bd = Bs + buf * 16384;
#pragma unroll
        for (int j = 0; j < 4; ++j) {
            int c = j * 4 + w;
            gload_lds16(Ab + (size_t)(c * 8 + srow) * 1024 + k0 + scolb, Ad + c * 1024);
            gload_lds16(Wb + (size_t)(c * 8 + srow) * 1024 + k0 + scolb, Bd + c * 1024);
        }
    };

    STAGE(0, 0);
    __syncthreads();
    for (int kt = 0; kt < 8; ++kt) {
        int cur = kt & 1;
        if (kt < 7) STAGE(kt + 1, cur ^ 1);
        const char* Ar = As + cur * 16384;
        const char* Br = Bs + cur * 16384;
#pragma unroll
        for (int ks = 0; ks < 2; ++ks) {
            int kb = (ks * 64 + lh * 16) ^ key16;
            i32x4 af[4], bfr[4];
#pragma unroll
            for (int mi = 0; mi < 4; ++mi) af[mi] = *(const i32x4*)&Ar[(wr * 64 + mi * 16 + lr) * 128 + kb];
#pragma unroll
            for (int ni = 0; ni < 4; ++ni) bfr[ni] = *(const i32x4*)&Br[(wc * 64 + ni * 16 + lr) * 128 + kb];
#pragma unroll
            for (int mi = 0; mi < 4; ++mi)
#pragma unroll
                for (int ni = 0; ni < 4; ++ni) acc[mi][ni] = mfma_i8(af[mi], bfr[ni], acc[mi][ni]);
        }
        __syncthreads();
    }
#pragma unroll
    for (int mi = 0; mi < 4; ++mi) {
        int mbase = bm * 128 + wr * 64 + mi * 16 + lh * 4;
#pragma unroll
        for (int ni = 0; ni < 4; ++ni) {
            int n = bn * 128 + wc * 64 + ni * 16 + lr;
            if (MODE == 1) {
                int b = mbase >> 11, t0 = mbase & 2047;
                int h = n >> 6, d = n & 63;
                ushort4 st;
                st.x = f2bf((float)acc[mi][ni][0] * s_w / asc[mbase + 0]);
                st.y = f2bf((float)acc[mi][ni][1] * s_w / asc[mbase + 1]);
                st.z = f2bf((float)acc[mi][ni][2] * s_w / asc[mbase + 2]);
                st.w = f2bf((float)acc[mi][ni][3] * s_w / asc[mbase + 3]);
                *(ushort4*)&((unsigned short*)outp)[(size_t)(b * 16 + h) * 131072 + (size_t)d * 2048 + t0] = st;
            } else {
#pragma unroll
                for (int i = 0; i < 4; ++i) {
                    int m = mbase + i;
                    float val = (float)acc[mi][ni][i] * s_w / asc[m];
                    if (MODE == 0) {
                        int b = m >> 11, t = m & 2047, h = n >> 6, d = n & 63;
                        ((unsigned short*)outp)[(size_t)(b * 16 + h) * 131072 + (size_t)t * 64 + d] = f2bf(val);
                    } else {
                        ((float*)outp)[(size_t)m * 1024 + n] = val;
                    }
                }
            }
        }
    }
}

__device__ __forceinline__ float sw_from_part(const float* part) {
    float s = 0.f;
#pragma unroll
    for (int i = 0; i < 32; ++i) s += part[i];
    return fmaxf(s * (1.f / 1048576.f), 1e-5f);
}

__global__ __launch_bounds__(256) void gemm_qkv(const signed char* __restrict__ abf,
                                                const float* __restrict__ ascale,
                                                const signed char* __restrict__ wq8,
                                                const float* __restrict__ part,
                                                unsigned short* __restrict__ qbf,
                                                unsigned short* __restrict__ kbf,
                                                unsigned short* __restrict__ vtb) {
    __shared__ alignas(16) char As[32768];
    __shared__ alignas(16) char Bs[32768];
    int z = blockIdx.z;
    const signed char* A = abf + (size_t)z * 4194304;
    const float* asc = ascale + z * 4096;
    const signed char* W = wq8 + (size_t)z * 1048576;
    float s_w = sw_from_part(part + z * 32);
    int bm = blockIdx.x, bn = blockIdx.y;
    if (z == 0) {
        gemm_core<0>(A, asc, W, s_w, qbf, bm, bn, As, Bs);
    } else if (z == 1) {
        gemm_core<0>(A, asc, W, s_w, kbf, bm, bn, As, Bs);
    } else {
        gemm_core<1>(A, asc, W, s_w, vtb, bm, bn, As, Bs);
    }
}

__global__ __launch_bounds__(256) void gemm_o(const signed char* __restrict__ A,
                                              const float* __restrict__ asc,
                                              const signed char* __restrict__ W,
                                              const float* __restrict__ part, float* __restrict__ outp) {
    __shared__ alignas(16) char As[32768];
    __shared__ alignas(16) char Bs[32768];
    float s_w = sw_from_part(part);
    gemm_core<2>(A, asc, W, s_w, outp, blockIdx.x, blockIdx.y, As, Bs);
}

// ---------------- flash attention (causal, 16 heads, D=64) ------------------
// 1024 blocks x 4 waves, 64 q-rows/block; wave w takes kv-tiles t = w, w+4, ..
// (disjoint -> bytes unchanged at 266 MB, but 12 waves/CU resident instead of
// 8 -> 1.5x more latency-hiding for the per-tile QK->exp2->LDS-RT->PV chain).
// FIXED-EXPONENT softmax (ps = exp2(min(p-32,0))): merge = plain O/l sums.
// Sequential 3-round LDS merge (one 16KB buffer). Guard t<ntiles for idle
// waves (small c): their zero state adds exactly 0.
__global__ __launch_bounds__(256) void attn(const unsigned short* __restrict__ qb,
                                            const unsigned short* __restrict__ kb,
                                            const unsigned short* __restrict__ vt,
                                            unsigned short* __restrict__ y) {
    int blk = blockIdx.x;
    int bh = blk & 31;
    int c = 31 - (blk >> 5);  // 64-row chunk 0..31, heaviest first
    int q0 = c << 6;
    int c2 = c << 1;          // first partially-masked kv-tile
    int ntiles = c2 + 2;
    int w = threadIdx.x >> 6;
    int l = threadIdx.x & 63;
    int lr = l & 15, lh = l >> 4;
    const unsigned short* qbase = qb + (size_t)bh * 131072;
    const unsigned short* kbase = kb + (size_t)bh * 131072;
    const unsigned short* vbase = vt + (size_t)bh * 131072;

    bf16x8 qf[4][2];
#pragma unroll
    for (int qt = 0; qt < 4; ++qt) {
        qf[qt][0] = *(const bf16x8*)&qbase[(size_t)(q0 + qt * 16 + lr) * 64 + lh * 8];
        qf[qt][1] = *(const bf16x8*)&qbase[(size_t)(q0 + qt * 16 + lr) * 64 + 32 + lh * 8];
    }

    f32x4 o[4][4] = {};  // [dt][qt]
    const float SC = 0.125f * 1.44269504f;  // 1/sqrt(64) * log2(e)
    float ls[4] = {0.f, 0.f, 0.f, 0.f};    // per-lane partial row-sums
    __shared__ alignas(16) unsigned short plds[4][4][16][40];  // 20.5 KB
    __shared__ alignas(16) float om[64][64];                    // 16 KB merge buf
    __shared__ float lm[4][16];

    auto LOADK = [&](int kv0, bf16x8* k) {
        k[0] = *(const bf16x8*)&kbase[(size_t)(kv0 + lr) * 64 + lh * 8];
        k[1] = *(const bf16x8*)&kbase[(size_t)(kv0 + lr) * 64 + 32 + lh * 8];
        k[2] = *(const bf16x8*)&kbase[(size_t)(kv0 + 16 + lr) * 64 + lh * 8];
        k[3] = *(const bf16x8*)&kbase[(size_t)(kv0 + 16 + lr) * 64 + 32 + lh * 8];
    };
    auto LOADV = [&](int kv0, bf16x8* v) {
        v[0] = *(const bf16x8*)&vbase[(size_t)(lr)*2048 + kv0 + lh * 8];
        v[1] = *(const bf16x8*)&vbase[(size_t)(16 + lr) * 2048 + kv0 + lh * 8];
        v[2] = *(const bf16x8*)&vbase[(size_t)(32 + lr) * 2048 + kv0 + lh * 8];
        v[3] = *(const bf16x8*)&vbase[(size_t)(48 + lr) * 2048 + kv0 + lh * 8];
    };

    auto PROCESS = [&](int t, bf16x8* k, bf16x8* v) {
        int kv0 = t << 5;
        __builtin_amdgcn_s_setprio(1);
        f32x4 sa[4], sb[4];
#pragma unroll
        for (int qt = 0; qt < 4; ++qt) {
            f32x4 x0 = {}, x1 = {};
            x0 = mfma16(k[0], qf[qt][0], x0);
            x0 = mfma16(k[1], qf[qt][1], x0);
            x1 = mfma16(k[2], qf[qt][0], x1);
            x1 = mfma16(k[3], qf[qt][1], x1);
            sa[qt] = x0;
            sb[qt] = x1;
        }
        __builtin_amdgcn_s_setprio(0);
        bool diag = (t >= c2);
#pragma unroll
        for (int qt = 0; qt < 4; ++qt) {
            float ps[8];
#pragma unroll
            for (int r = 0; r < 4; ++r) {
                ps[r] = exp2_fast(fminf(fmaf(sa[qt][r], SC, -32.f), 0.f));
                ps[r + 4] = exp2_fast(fminf(fmaf(sb[qt][r], SC, -32.f), 0.f));
            }
            if (diag) {
                int qrow = q0 + qt * 16 + lr;
#pragma unroll
                for (int r = 0; r < 4; ++r) {
                    if (kv0 + lh * 4 + r > qrow) ps[r] = 0.f;
                    if (kv0 + 16 + lh * 4 + r > qrow) ps[r + 4] = 0.f;
                }
            }
            ls[qt] += ((ps[0] + ps[1]) + (ps[2] + ps[3])) + ((ps[4] + ps[5]) + (ps[6] + ps[7]));
            uint2 wlo, whi;
            wlo.x = cvtpk_bf16(ps[0], ps[1]);
            wlo.y = cvtpk_bf16(ps[2], ps[3]);
            whi.x = cvtpk_bf16(ps[4], ps[5]);
            whi.y = cvtpk_bf16(ps[6], ps[7]);
            *(uint2*)&plds[w][qt][lr][lh * 4] = wlo;
            *(uint2*)&plds[w][qt][lr][16 + lh * 4] = whi;
        }
        bf16x8 pf[4];
#pragma unroll
        for (int qt = 0; qt < 4; ++qt) pf[qt] = *(const bf16x8*)&plds[w][qt][lr][lh * 8];
        __builtin_amdgcn_s_setprio(1);
#pragma unroll
        for (int dt = 0; dt < 4; ++dt) {
            bf16x8 vv = v[dt];
#pragma unroll
            for (int qt = 0; qt < 4; ++qt) o[dt][qt] = mfma16(vv, pf[qt], o[dt][qt]);
        }
        __builtin_amdgcn_s_setprio(0);
    };

    // wave w owns kv-tiles t = w, w+4, ... (register double-buffered)
    if (w < ntiles) {
        bf16x8 kA[4], vA[4], kB[4], vB[4];
        int t = w;
        LOADK(t << 5, kA);
        LOADV(t << 5, vA);
        while (true) {
            if (t + 4 < ntiles) { LOADK((t + 4) << 5, kB); LOADV((t + 4) << 5, vB); }
            PROCESS(t, kA, vA);
            t += 4;
            if (t >= ntiles) break;
            if (t + 4 < ntiles) { LOADK((t + 4) << 5, kA); LOADV((t + 4) << 5, vA); }
            PROCESS(t, kB, vB);
            t += 4;
            if (t >= ntiles) break;
        }
    }

    // finish per-row sums (4 lane-replicas per row)
#pragma unroll
    for (int qt = 0; qt < 4; ++qt) {
        ls[qt] += __shfl_xor(ls[qt], 16);
        ls[qt] += __shfl_xor(ls[qt], 32);
    }

    // ---- sequential 3-round merge into wave0 (plain sums) ----
#pragma unroll
    for (int r = 1; r < 4; ++r) {
        __syncthreads();
        if (w == r) {
#pragma unroll
            for (int qt = 0; qt < 4; ++qt) {
#pragma unroll
                for (int dt = 0; dt < 4; ++dt) {
                    float4 st;
                    st.x = o[dt][qt][0];
                    st.y = o[dt][qt][1];
                    st.z = o[dt][qt][2];
                    st.w = o[dt][qt][3];
                    *(float4*)&om[qt * 16 + lr][dt * 16 + lh * 4] = st;
                }
                if (lh == 0) lm[qt][lr] = ls[qt];
            }
        }
        __syncthreads();
        if (w == 0) {
#pragma unroll
            for (int qt = 0; qt < 4; ++qt) {
#pragma unroll
                for (int dt = 0; dt < 4; ++dt) {
                    float4 v1 = *(float4*)&om[qt * 16 + lr][dt * 16 + lh * 4];
                    o[dt][qt][0] += v1.x;
                    o[dt][qt][1] += v1.y;
                    o[dt][qt][2] += v1.z;
                    o[dt][qt][3] += v1.w;
                }
                ls[qt] += lm[qt][lr];
            }
        }
    }
    if (w == 0) {
        int b = bh >> 4, h = bh & 15;
#pragma unroll
        for (int qt = 0; qt < 4; ++qt) {
            float invl = 1.f / ls[qt];
            int qrow = q0 + qt * 16 + lr;
            unsigned short* yr = y + (size_t)(b * 2048 + qrow) * 1024 + h * 64;
#pragma unroll
            for (int dt = 0; dt < 4; ++dt) {
                float r0 = o[dt][qt][0] * invl;
                float r1 = o[dt][qt][1] * invl;
                float r2 = o[dt][qt][2] * invl;
                float r3 = o[dt][qt][3] * invl;
                uint2 pk;
                pk.x = cvtpk_bf16(r0, r1);
                pk.y = cvtpk_bf16(r2, r3);
                *(uint2*)&yr[dt * 16 + lh * 4] = pk;
            }
        }
    }
}

extern "C" void kernel_launch(void* const* d_in, const int* in_sizes, int n_in,
                              void* d_out, int out_size, void* d_ws, size_t ws_size,
                              hipStream_t stream) {
    const float* x  = (const float*)d_in[0];
    const float* wq = (const float*)d_in[1];
    const float* wk = (const float*)d_in[2];
    const float* wv = (const float*)d_in[3];
    const float* wo = (const float*)d_in[4];
    const float* gq = (const float*)d_in[5];
    const float* gk = (const float*)d_in[6];
    const float* gv = (const float*)d_in[7];
    const float* go = (const float*)d_in[8];

    char* ws = (char*)d_ws;
    size_t off = 0;
    auto alloc = [&](size_t bytes) {
        size_t o = off;
        off += (bytes + 255) & ~(size_t)255;
        return o;
    };
    float* part = (float*)(ws + alloc(128 * 4));
    signed char* wq8 = (signed char*)(ws + alloc(4ull * 1048576));
    signed char* abf = (signed char*)(ws + alloc(3ull * 4194304));
    float* asc = (float*)(ws + alloc(3ull * 4096 * 4));
    unsigned short* qbf = (unsigned short*)(ws + alloc(4194304ull * 2));
    unsigned short* kbf = (unsigned short*)(ws + alloc(4194304ull * 2));
    unsigned short* vtb = (unsigned short*)(ws + alloc(4194304ull * 2));
    unsigned short* ybf16 = (unsigned short*)(ws + alloc(4194304ull * 2));  // [B,T,C] bf16
    signed char* ybf = (signed char*)(ws + alloc(4194304ull));
    float* ysc = (float*)(ws + alloc(4096 * 4));
    (void)ws_size; (void)in_sizes; (void)n_in; (void)out_size;

    prep<<<4224, 256, 0, stream>>>(x, gq, gk, gv, abf, asc, wq, wk, wv, wo, part);
    wquant<<<256, 256, 0, stream>>>(wq, wk, wv, wo, part, wq8);
    gemm_qkv<<<dim3(32, 8, 3), 256, 0, stream>>>(abf, asc, wq8, part, qbf, kbf, vtb);
    attn<<<1024, 256, 0, stream>>>(qbf, kbf, vtb, ybf16);
    actquant_y<<<4096, 256, 0, stream>>>(ybf16, go, ybf, ysc);
    gemm_o<<<dim3(32, 8), 256, 0, stream>>>(ybf, ysc, wq8 + 3ull * 1048576, part + 96, (float*)d_out);
}

// Round 18
// 118.185 us; speedup vs baseline: 1.2709x; 1.2709x over previous
//
#include <hip/hip_runtime.h>
#include <hip/hip_bf16.h>

// B=2, T=2048, C=1024, H=16, D=64, M=B*T=4096
// GEMMs: exact integer math via i8 MFMA (i32 accum, |dot| <= 130K exact).

typedef __attribute__((ext_vector_type(8))) short bf16x8;
typedef __attribute__((ext_vector_type(4))) float f32x4;
typedef __attribute__((ext_vector_type(4))) int i32x4;

__device__ __forceinline__ f32x4 mfma16(bf16x8 a, bf16x8 b, f32x4 c) {
    return __builtin_amdgcn_mfma_f32_16x16x32_bf16(a, b, c, 0, 0, 0);
}

__device__ __forceinline__ i32x4 mfma_i8(i32x4 a, i32x4 b, i32x4 c) {
    return __builtin_amdgcn_mfma_i32_16x16x64_i8(a, b, c, 0, 0, 0);
}

__device__ __forceinline__ unsigned short f2bf(float f) {
    unsigned int u = __float_as_uint(f);
    unsigned int r = (u + 0x7fffu + ((u >> 16) & 1u)) >> 16;
    return (unsigned short)r;
}

__device__ __forceinline__ float bf2f(unsigned short u) {
    return __uint_as_float(((unsigned int)u) << 16);
}

__device__ __forceinline__ unsigned int cvtpk_bf16(float lo, float hi) {
    unsigned int r;
    asm("v_cvt_pk_bf16_f32 %0, %1, %2" : "=v"(r) : "v"(lo), "v"(hi));
    return r;
}

__device__ __forceinline__ float exp2_fast(float x) {
    float r;
    asm("v_exp_f32 %0, %1" : "=v"(r) : "v"(x));
    return r;
}

__device__ __forceinline__ void gload_lds16(const void* g, void* l) {
    __builtin_amdgcn_global_load_lds((const __attribute__((address_space(1))) unsigned int*)g,
                                     (__attribute__((address_space(3))) unsigned int*)l, 16, 0, 0);
}

__device__ __forceinline__ int pack4i8(float a, float b, float c, float d) {
    unsigned int u = ((unsigned int)((int)a & 255)) | (((unsigned int)((int)b & 255)) << 8) |
                     (((unsigned int)((int)c & 255)) << 16) | (((unsigned int)((int)d & 255)) << 24);
    return (int)u;
}

__device__ __forceinline__ float wredsum(float v) {
#pragma unroll
    for (int o = 32; o > 0; o >>= 1) v += __shfl_xor(v, o);
    return v;
}
__device__ __forceinline__ float wredmax(float v) {
#pragma unroll
    for (int o = 32; o > 0; o >>= 1) v = fmaxf(v, __shfl_xor(v, o));
    return v;
}

// ------- fused: rmsnorm+absmax-quant of x (3 planes) AND weight |w| partials -
// blocks 0..4095: actquant on x row m; blocks 4096..4223: wabssum partials.
__global__ __launch_bounds__(256) void prep(const float* __restrict__ x, const float* __restrict__ g0,
                                            const float* __restrict__ g1, const float* __restrict__ g2,
                                            signed char* __restrict__ aq, float* __restrict__ ascale,
                                            const float* __restrict__ w0, const float* __restrict__ w1,
                                            const float* __restrict__ w2, const float* __restrict__ w3,
                                            float* __restrict__ part) {
    int tid = threadIdx.x;
    int wid = tid >> 6, lid = tid & 63;
    __shared__ float red[4];
    if (blockIdx.x >= 4096) {
        int bb = blockIdx.x - 4096;
        int widx = bb >> 5, b = bb & 31;
        const float* w = (widx == 0) ? w0 : (widx == 1) ? w1 : (widx == 2) ? w2 : w3;
        const float4* w4 = (const float4*)w;
        float s = 0.f;
        int base = b * 8192 + tid;
#pragma unroll
        for (int i = 0; i < 32; ++i) {
            float4 v = w4[base + i * 256];
            s += fabsf(v.x) + fabsf(v.y) + fabsf(v.z) + fabsf(v.w);
        }
        s = wredsum(s);
        if (lid == 0) red[wid] = s;
        __syncthreads();
        if (tid == 0) part[bb] = red[0] + red[1] + red[2] + red[3];
        return;
    }
    int m = blockIdx.x;
    float4 xv = ((const float4*)(x + (size_t)m * 1024))[tid];
    float ss = xv.x * xv.x + xv.y * xv.y + xv.z * xv.z + xv.w * xv.w;
    ss = wredsum(ss);
    if (lid == 0) red[wid] = ss;
    __syncthreads();
    float rstd = rsqrtf((red[0] + red[1] + red[2] + red[3]) * (1.f / 1024.f) + 1e-6f);
    const float* gs[3] = {g0, g1, g2};
#pragma unroll
    for (int p = 0; p < 3; ++p) {
        float4 gv = ((const float4*)gs[p])[tid];
        float a0 = xv.x * gv.x * rstd, a1 = xv.y * gv.y * rstd;
        float a2 = xv.z * gv.z * rstd, a3 = xv.w * gv.w * rstd;
        float am = fmaxf(fmaxf(fabsf(a0), fabsf(a1)), fmaxf(fabsf(a2), fabsf(a3)));
        am = wredmax(am);
        __syncthreads();
        if (lid == 0) red[wid] = am;
        __syncthreads();
        float rm = fmaxf(fmaxf(red[0], red[1]), fmaxf(red[2], red[3]));
        float scale = 127.f / fmaxf(rm, 1e-5f);
        float q0 = fminf(fmaxf(rintf(a0 * scale), -128.f), 127.f);
        float q1 = fminf(fmaxf(rintf(a1 * scale), -128.f), 127.f);
        float q2 = fminf(fmaxf(rintf(a2 * scale), -128.f), 127.f);
        float q3 = fminf(fmaxf(rintf(a3 * scale), -128.f), 127.f);
        ((int*)(aq + (size_t)p * 4194304 + (size_t)m * 1024))[tid] = pack4i8(q0, q1, q2, q3);
        if (tid == 0) ascale[p * 4096 + m] = scale;
    }
}

// ---------------- ternary weight quant -> i8 {-1,0,1} -----------------------
__global__ __launch_bounds__(256) void wquant(const float* __restrict__ w0, const float* __restrict__ w1,
                                              const float* __restrict__ w2, const float* __restrict__ w3,
                                              const float* __restrict__ part, signed char* __restrict__ wq8) {
    int widx = blockIdx.x >> 6, b = blockIdx.x & 63;
    const float* w = (widx == 0) ? w0 : (widx == 1) ? w1 : (widx == 2) ? w2 : w3;
    float s = 0.f;
#pragma unroll
    for (int i = 0; i < 32; ++i) s += part[widx * 32 + i];
    s = fmaxf(s * (1.f / 1048576.f), 1e-5f);
    float inv = 1.f / s;
    const float4* w4 = (const float4*)w;
    int* dst = (int*)(wq8 + (size_t)widx * 1048576);
    int tid = threadIdx.x;
#pragma unroll
    for (int it = 0; it < 16; ++it) {
        int i4 = b * 4096 + it * 256 + tid;
        float4 v = w4[i4];
        float q0 = fminf(fmaxf(rintf(v.x * inv), -1.f), 1.f);
        float q1 = fminf(fmaxf(rintf(v.y * inv), -1.f), 1.f);
        float q2 = fminf(fmaxf(rintf(v.z * inv), -1.f), 1.f);
        float q3 = fminf(fmaxf(rintf(v.w * inv), -1.f), 1.f);
        dst[i4] = pack4i8(q0, q1, q2, q3);
    }
}

// ------- rmsnorm+absmax-quant of y (bf16 input, 1 plane) --------------------
__global__ __launch_bounds__(256) void actquant_y(const unsigned short* __restrict__ y,
                                                  const float* __restrict__ g,
                                                  signed char* __restrict__ aq, float* __restrict__ ascale) {
    int m = blockIdx.x, tid = threadIdx.x;
    int wid = tid >> 6, lid = tid & 63;
    __shared__ float red[4];
    ushort4 uv = ((const ushort4*)(y + (size_t)m * 1024))[tid];
    float4 xv;
    xv.x = bf2f(uv.x);
    xv.y = bf2f(uv.y);
    xv.z = bf2f(uv.z);
    xv.w = bf2f(uv.w);
    float ss = xv.x * xv.x + xv.y * xv.y + xv.z * xv.z + xv.w * xv.w;
    ss = wredsum(ss);
    if (lid == 0) red[wid] = ss;
    __syncthreads();
    float rstd = rsqrtf((red[0] + red[1] + red[2] + red[3]) * (1.f / 1024.f) + 1e-6f);
    float4 gv = ((const float4*)g)[tid];
    float a0 = xv.x * gv.x * rstd, a1 = xv.y * gv.y * rstd;
    float a2 = xv.z * gv.z * rstd, a3 = xv.w * gv.w * rstd;
    float am = fmaxf(fmaxf(fabsf(a0), fabsf(a1)), fmaxf(fabsf(a2), fabsf(a3)));
    am = wredmax(am);
    __syncthreads();
    if (lid == 0) red[wid] = am;
    __syncthreads();
    float rm = fmaxf(fmaxf(red[0], red[1]), fmaxf(red[2], red[3]));
    float scale = 127.f / fmaxf(rm, 1e-5f);
    float q0 = fminf(fmaxf(rintf(a0 * scale), -128.f), 127.f);
    float q1 = fminf(fmaxf(rintf(a1 * scale), -128.f), 127.f);
    float q2 = fminf(fmaxf(rintf(a2 * scale), -128.f), 127.f);
    float q3 = fminf(fmaxf(rintf(a3 * scale), -128.f), 127.f);
    ((int*)(aq + (size_t)m * 1024))[tid] = pack4i8(q0, q1, q2, q3);
    if (tid == 0) ascale[m] = scale;
}

// ------------- 128x128-tile i8 GEMM core (dbuf + XOR-swizzled LDS) ----------
template <int MODE>
__device__ __forceinline__ void gemm_core(const signed char* __restrict__ A,
                                          const float* __restrict__ asc,
                                          const signed char* __restrict__ W, float s_w,
                                          void* __restrict__ outp, int bm, int bn,
                                          char* As, char* Bs) {
    int tid = threadIdx.x;
    int w = tid >> 6, l = tid & 63;
    int wr = w >> 1, wc = w & 1;
    int lr = l & 15, lh = l >> 4;
    i32x4 acc[4][4] = {};
    int srow = l >> 3;
    int scolb = (((l & 7) ^ srow)) * 16;
    int key16 = (lr & 7) * 16;
    const signed char* Ab = A + (size_t)(bm * 128) * 1024;
    const signed char* Wb = W + (size_t)(bn * 128) * 1024;

    auto STAGE = [&](int kt, int buf) {
        int k0 = kt * 128;
        char* Ad = As + buf * 16384;
        char* Bd = Bs + buf * 16384;
#pragma unroll
        for (int j = 0; j < 4; ++j) {
            int c = j * 4 + w;
            gload_lds16(Ab + (size_t)(c * 8 + srow) * 1024 + k0 + scolb, Ad + c * 1024);
            gload_lds16(Wb + (size_t)(c * 8 + srow) * 1024 + k0 + scolb, Bd + c * 1024);
        }
    };

    STAGE(0, 0);
    __syncthreads();
    for (int kt = 0; kt < 8; ++kt) {
        int cur = kt & 1;
        if (kt < 7) STAGE(kt + 1, cur ^ 1);
        const char* Ar = As + cur * 16384;
        const char* Br = Bs + cur * 16384;
#pragma unroll
        for (int ks = 0; ks < 2; ++ks) {
            int kb = (ks * 64 + lh * 16) ^ key16;
            i32x4 af[4], bfr[4];
#pragma unroll
            for (int mi = 0; mi < 4; ++mi) af[mi] = *(const i32x4*)&Ar[(wr * 64 + mi * 16 + lr) * 128 + kb];
#pragma unroll
            for (int ni = 0; ni < 4; ++ni) bfr[ni] = *(const i32x4*)&Br[(wc * 64 + ni * 16 + lr) * 128 + kb];
#pragma unroll
            for (int mi = 0; mi < 4; ++mi)
#pragma unroll
                for (int ni = 0; ni < 4; ++ni) acc[mi][ni] = mfma_i8(af[mi], bfr[ni], acc[mi][ni]);
        }
        __syncthreads();
    }
#pragma unroll
    for (int mi = 0; mi < 4; ++mi) {
        int mbase = bm * 128 + wr * 64 + mi * 16 + lh * 4;
#pragma unroll
        for (int ni = 0; ni < 4; ++ni) {
            int n = bn * 128 + wc * 64 + ni * 16 + lr;
            if (MODE == 1) {
                int b = mbase >> 11, t0 = mbase & 2047;
                int h = n >> 6, d = n & 63;
                ushort4 st;
                st.x = f2bf((float)acc[mi][ni][0] * s_w / asc[mbase + 0]);
                st.y = f2bf((float)acc[mi][ni][1] * s_w / asc[mbase + 1]);
                st.z = f2bf((float)acc[mi][ni][2] * s_w / asc[mbase + 2]);
                st.w = f2bf((float)acc[mi][ni][3] * s_w / asc[mbase + 3]);
                *(ushort4*)&((unsigned short*)outp)[(size_t)(b * 16 + h) * 131072 + (size_t)d * 2048 + t0] = st;
            } else {
#pragma unroll
                for (int i = 0; i < 4; ++i) {
                    int m = mbase + i;
                    float val = (float)acc[mi][ni][i] * s_w / asc[m];
                    if (MODE == 0) {
                        int b = m >> 11, t = m & 2047, h = n >> 6, d = n & 63;
                        ((unsigned short*)outp)[(size_t)(b * 16 + h) * 131072 + (size_t)t * 64 + d] = f2bf(val);
                    } else {
                        ((float*)outp)[(size_t)m * 1024 + n] = val;
                    }
                }
            }
        }
    }
}

__device__ __forceinline__ float sw_from_part(const float* part) {
    float s = 0.f;
#pragma unroll
    for (int i = 0; i < 32; ++i) s += part[i];
    return fmaxf(s * (1.f / 1048576.f), 1e-5f);
}

__global__ __launch_bounds__(256) void gemm_qkv(const signed char* __restrict__ abf,
                                                const float* __restrict__ ascale,
                                                const signed char* __restrict__ wq8,
                                                const float* __restrict__ part,
                                                unsigned short* __restrict__ qbf,
                                                unsigned short* __restrict__ kbf,
                                                unsigned short* __restrict__ vtb) {
    __shared__ alignas(16) char As[32768];
    __shared__ alignas(16) char Bs[32768];
    int z = blockIdx.z;
    const signed char* A = abf + (size_t)z * 4194304;
    const float* asc = ascale + z * 4096;
    const signed char* W = wq8 + (size_t)z * 1048576;
    float s_w = sw_from_part(part + z * 32);
    int bm = blockIdx.x, bn = blockIdx.y;
    if (z == 0) {
        gemm_core<0>(A, asc, W, s_w, qbf, bm, bn, As, Bs);
    } else if (z == 1) {
        gemm_core<0>(A, asc, W, s_w, kbf, bm, bn, As, Bs);
    } else {
        gemm_core<1>(A, asc, W, s_w, vtb, bm, bn, As, Bs);
    }
}

__global__ __launch_bounds__(256) void gemm_o(const signed char* __restrict__ A,
                                              const float* __restrict__ asc,
                                              const signed char* __restrict__ W,
                                              const float* __restrict__ part, float* __restrict__ outp) {
    __shared__ alignas(16) char As[32768];
    __shared__ alignas(16) char Bs[32768];
    float s_w = sw_from_part(part);
    gemm_core<2>(A, asc, W, s_w, outp, blockIdx.x, blockIdx.y, As, Bs);
}

// ---------------- flash attention (causal, 16 heads, D=64) ------------------
// 1024 blocks x 2 waves, 64 q-rows/block, kv-split across waves (t = w, w+2..).
// FIXED-EXPONENT softmax: ps = exp2(min(p - 32, 0)); no max tracking, no
// per-tile reduces; l per-lane, reduced once at end; wave merge = plain sums.
// Output written as bf16 (halves attn write + actquant_y read traffic).
__global__ __launch_bounds__(128) void attn(const unsigned short* __restrict__ qb,
                                            const unsigned short* __restrict__ kb,
                                            const unsigned short* __restrict__ vt,
                                            unsigned short* __restrict__ y) {
    int blk = blockIdx.x;
    int bh = blk & 31;
    int c = 31 - (blk >> 5);  // 64-row chunk 0..31, heaviest first
    int q0 = c << 6;
    int c2 = c << 1;          // first partially-masked kv-tile
    int ntiles = c2 + 2;
    int w = threadIdx.x >> 6;
    int l = threadIdx.x & 63;
    int lr = l & 15, lh = l >> 4;
    const unsigned short* qbase = qb + (size_t)bh * 131072;
    const unsigned short* kbase = kb + (size_t)bh * 131072;
    const unsigned short* vbase = vt + (size_t)bh * 131072;

    bf16x8 qf[4][2];
#pragma unroll
    for (int qt = 0; qt < 4; ++qt) {
        qf[qt][0] = *(const bf16x8*)&qbase[(size_t)(q0 + qt * 16 + lr) * 64 + lh * 8];
        qf[qt][1] = *(const bf16x8*)&qbase[(size_t)(q0 + qt * 16 + lr) * 64 + 32 + lh * 8];
    }

    f32x4 o[4][4] = {};  // [dt][qt]
    const float SC = 0.125f * 1.44269504f;  // 1/sqrt(64) * log2(e)
    float ls[4] = {0.f, 0.f, 0.f, 0.f};    // per-lane partial row-sums
    __shared__ alignas(16) unsigned short plds[2][4][16][40];
    __shared__ alignas(16) float om[64][64];  // wave1's unnormalized O
    __shared__ float lm[4][16];               // wave1's l partials (reduced)

    auto LOADK = [&](int kv0, bf16x8* k) {
        k[0] = *(const bf16x8*)&kbase[(size_t)(kv0 + lr) * 64 + lh * 8];
        k[1] = *(const bf16x8*)&kbase[(size_t)(kv0 + lr) * 64 + 32 + lh * 8];
        k[2] = *(const bf16x8*)&kbase[(size_t)(kv0 + 16 + lr) * 64 + lh * 8];
        k[3] = *(const bf16x8*)&kbase[(size_t)(kv0 + 16 + lr) * 64 + 32 + lh * 8];
    };
    auto LOADV = [&](int kv0, bf16x8* v) {
        v[0] = *(const bf16x8*)&vbase[(size_t)(lr)*2048 + kv0 + lh * 8];
        v[1] = *(const bf16x8*)&vbase[(size_t)(16 + lr) * 2048 + kv0 + lh * 8];
        v[2] = *(const bf16x8*)&vbase[(size_t)(32 + lr) * 2048 + kv0 + lh * 8];
        v[3] = *(const bf16x8*)&vbase[(size_t)(48 + lr) * 2048 + kv0 + lh * 8];
    };

    auto PROCESS = [&](int t, bf16x8* k, bf16x8* v) {
        int kv0 = t << 5;
        __builtin_amdgcn_s_setprio(1);
        f32x4 sa[4], sb[4];
#pragma unroll
        for (int qt = 0; qt < 4; ++qt) {
            f32x4 x0 = {}, x1 = {};
            x0 = mfma16(k[0], qf[qt][0], x0);
            x0 = mfma16(k[1], qf[qt][1], x0);
            x1 = mfma16(k[2], qf[qt][0], x1);
            x1 = mfma16(k[3], qf[qt][1], x1);
            sa[qt] = x0;
            sb[qt] = x1;
        }
        __builtin_amdgcn_s_setprio(0);
        bool diag = (t >= c2);
#pragma unroll
        for (int qt = 0; qt < 4; ++qt) {
            float ps[8];
#pragma unroll
            for (int r = 0; r < 4; ++r) {
                ps[r] = exp2_fast(fminf(fmaf(sa[qt][r], SC, -32.f), 0.f));
                ps[r + 4] = exp2_fast(fminf(fmaf(sb[qt][r], SC, -32.f), 0.f));
            }
            if (diag) {
                int qrow = q0 + qt * 16 + lr;
#pragma unroll
                for (int r = 0; r < 4; ++r) {
                    if (kv0 + lh * 4 + r > qrow) ps[r] = 0.f;
                    if (kv0 + 16 + lh * 4 + r > qrow) ps[r + 4] = 0.f;
                }
            }
            ls[qt] += ((ps[0] + ps[1]) + (ps[2] + ps[3])) + ((ps[4] + ps[5]) + (ps[6] + ps[7]));
            uint2 wlo, whi;
            wlo.x = cvtpk_bf16(ps[0], ps[1]);
            wlo.y = cvtpk_bf16(ps[2], ps[3]);
            whi.x = cvtpk_bf16(ps[4], ps[5]);
            whi.y = cvtpk_bf16(ps[6], ps[7]);
            *(uint2*)&plds[w][qt][lr][lh * 4] = wlo;
            *(uint2*)&plds[w][qt][lr][16 + lh * 4] = whi;
        }
        bf16x8 pf[4];
#pragma unroll
        for (int qt = 0; qt < 4; ++qt) pf[qt] = *(const bf16x8*)&plds[w][qt][lr][lh * 8];
        __builtin_amdgcn_s_setprio(1);
#pragma unroll
        for (int dt = 0; dt < 4; ++dt) {
            bf16x8 vv = v[dt];
#pragma unroll
            for (int qt = 0; qt < 4; ++qt) o[dt][qt] = mfma16(vv, pf[qt], o[dt][qt]);
        }
        __builtin_amdgcn_s_setprio(0);
    };

    // wave w owns kv-tiles t = w, w+2, ... (register double-buffered)
    {
        bf16x8 kA[4], vA[4], kB[4], vB[4];
        int t = w;
        LOADK(t << 5, kA);
        LOADV(t << 5, vA);
        while (true) {
            if (t + 2 < ntiles) { LOADK((t + 2) << 5, kB); LOADV((t + 2) << 5, vB); }
            PROCESS(t, kA, vA);
            t += 2;
            if (t >= ntiles) break;
            if (t + 2 < ntiles) { LOADK((t + 2) << 5, kA); LOADV((t + 2) << 5, vA); }
            PROCESS(t, kB, vB);
            t += 2;
            if (t >= ntiles) break;
        }
    }

    // finish per-row sums (4 lane-replicas per row)
#pragma unroll
    for (int qt = 0; qt < 4; ++qt) {
        ls[qt] += __shfl_xor(ls[qt], 16);
        ls[qt] += __shfl_xor(ls[qt], 32);
    }

    // ---- merge wave1 into wave0 (plain sums: same fixed exponent) ----
    if (w == 1) {
#pragma unroll
        for (int qt = 0; qt < 4; ++qt) {
#pragma unroll
            for (int dt = 0; dt < 4; ++dt) {
                float4 st;
                st.x = o[dt][qt][0];
                st.y = o[dt][qt][1];
                st.z = o[dt][qt][2];
                st.w = o[dt][qt][3];
                *(float4*)&om[qt * 16 + lr][dt * 16 + lh * 4] = st;
            }
            if (lh == 0) lm[qt][lr] = ls[qt];
        }
    }
    __syncthreads();
    if (w == 0) {
        int b = bh >> 4, h = bh & 15;
#pragma unroll
        for (int qt = 0; qt < 4; ++qt) {
            float invl = 1.f / (ls[qt] + lm[qt][lr]);
            int qrow = q0 + qt * 16 + lr;
            unsigned short* yr = y + (size_t)(b * 2048 + qrow) * 1024 + h * 64;
#pragma unroll
            for (int dt = 0; dt < 4; ++dt) {
                float4 v1 = *(float4*)&om[qt * 16 + lr][dt * 16 + lh * 4];
                float r0 = (o[dt][qt][0] + v1.x) * invl;
                float r1 = (o[dt][qt][1] + v1.y) * invl;
                float r2 = (o[dt][qt][2] + v1.z) * invl;
                float r3 = (o[dt][qt][3] + v1.w) * invl;
                uint2 pk;
                pk.x = cvtpk_bf16(r0, r1);
                pk.y = cvtpk_bf16(r2, r3);
                *(uint2*)&yr[dt * 16 + lh * 4] = pk;
            }
        }
    }
}

extern "C" void kernel_launch(void* const* d_in, const int* in_sizes, int n_in,
                              void* d_out, int out_size, void* d_ws, size_t ws_size,
                              hipStream_t stream) {
    const float* x  = (const float*)d_in[0];
    const float* wq = (const float*)d_in[1];
    const float* wk = (const float*)d_in[2];
    const float* wv = (const float*)d_in[3];
    const float* wo = (const float*)d_in[4];
    const float* gq = (const float*)d_in[5];
    const float* gk = (const float*)d_in[6];
    const float* gv = (const float*)d_in[7];
    const float* go = (const float*)d_in[8];

    char* ws = (char*)d_ws;
    size_t off = 0;
    auto alloc = [&](size_t bytes) {
        size_t o = off;
        off += (bytes + 255) & ~(size_t)255;
        return o;
    };
    float* part = (float*)(ws + alloc(128 * 4));
    signed char* wq8 = (signed char*)(ws + alloc(4ull * 1048576));
    signed char* abf = (signed char*)(ws + alloc(3ull * 4194304));
    float* asc = (float*)(ws + alloc(3ull * 4096 * 4));
    unsigned short* qbf = (unsigned short*)(ws + alloc(4194304ull * 2));
    unsigned short* kbf = (unsigned short*)(ws + alloc(4194304ull * 2));
    unsigned short* vtb = (unsigned short*)(ws + alloc(4194304ull * 2));
    unsigned short* ybf16 = (unsigned short*)(ws + alloc(4194304ull * 2));  // [B,T,C] bf16
    signed char* ybf = (signed char*)(ws + alloc(4194304ull));
    float* ysc = (float*)(ws + alloc(4096 * 4));
    (void)ws_size; (void)in_sizes; (void)n_in; (void)out_size;

    prep<<<4224, 256, 0, stream>>>(x, gq, gk, gv, abf, asc, wq, wk, wv, wo, part);
    wquant<<<256, 256, 0, stream>>>(wq, wk, wv, wo, part, wq8);
    gemm_qkv<<<dim3(32, 8, 3), 256, 0, stream>>>(abf, asc, wq8, part, qbf, kbf, vtb);
    attn<<<1024, 128, 0, stream>>>(qbf, kbf, vtb, ybf16);
    actquant_y<<<4096, 256, 0, stream>>>(ybf16, go, ybf, ysc);
    gemm_o<<<dim3(32, 8), 256, 0, stream>>>(ybf, ysc, wq8 + 3ull * 1048576, part + 96, (float*)d_out);
}